// Round 10
// baseline (41.771 us; speedup 1.0000x reference)
//
#include <hip/hip_runtime.h>
#include <hip/hip_bf16.h>

#define NG 128
#define NT 16
#define LN2 0.6931471805599453f
#define L2E 1.4426950408889634f
#define EXP2F(x) __builtin_amdgcn_exp2f(x)

__global__ void zero_out(float* __restrict__ out) {
    if (threadIdx.x == 0) out[0] = 0.0f;
}

__device__ __forceinline__ unsigned short f2bf(float x) {
    unsigned b = __float_as_uint(x);
    unsigned r = (b + 0x7FFFu + ((b >> 16) & 1u)) >> 16;   // RNE
    return (unsigned short)r;
}
__device__ __forceinline__ float bf_lo(unsigned u) { return __uint_as_float(u << 16); }
__device__ __forceinline__ float bf_hi(unsigned u) { return __uint_as_float(u & 0xFFFF0000u); }

// Single-phase: block = 64 samples x 128 genes, 8 waves x 16 genes each.
// Tables built IN-BLOCK (no setup kernel, no ws): gtab/lgtab fp32,
// emd+md packed bf16 -> 4 ds_read_b128 per gene instead of 8.
__global__ __launch_bounds__(512, 4) void nb_main(const float* __restrict__ delta,
                                                  const float* __restrict__ beta,
                                                  const float* __restrict__ phi,
                                                  const float* __restrict__ mo,
                                                  const float* __restrict__ expr,
                                                  const float* __restrict__ cov,
                                                  const float* __restrict__ sfv,
                                                  float* __restrict__ out,
                                                  int ns) {
    // 22528 B total; reduction tree aliases the front after tables are dead
    __shared__ __align__(16) unsigned char s_mem[22528];
    float*          s_gt  = (float*)s_mem;              // [128][8] f32 {b0..3,phi,...}
    unsigned short* s_e16 = (unsigned short*)(s_mem + 4096);  // [128][32] bf16 {emd[16],md[16]}
    float*          s_lg  = (float*)(s_mem + 12288);    // [128][20] f32

    const int tid = threadIdx.x;

    // ---- in-block table build: threads 0..127, one gene each ----
    if (tid < NG) {
        const int g = tid;
        const float lnfact[20] = {
            0.0f, 0.0f, 0.69314718f, 1.79175947f, 3.17805383f,
            4.78749174f, 6.57925121f, 8.52516132f, 10.60460286f, 12.80182744f,
            15.10441253f, 17.50230781f, 19.98721446f, 22.55216381f, 25.19122114f,
            27.89927134f, 30.67186007f, 33.50507341f, 36.39544517f, 39.33988415f};

        float ph = fminf(fmaxf(phi[g], 1.0f), 100.0f);
        float plp = ph * __logf(ph);

        s_gt[g * 8 + 0] = beta[0 * NG + g];
        s_gt[g * 8 + 1] = beta[1 * NG + g];
        s_gt[g * 8 + 2] = beta[2 * NG + g];
        s_gt[g * 8 + 3] = beta[3 * NG + g];
        s_gt[g * 8 + 4] = ph;

#pragma unroll
        for (int t = 0; t < NT; ++t) {
            float md = mo[g * NT + t] * delta[g * NT + t];
            s_e16[g * 32 + t]      = f2bf(__expf(md));
            s_e16[g * 32 + 16 + t] = f2bf(md);
        }

        float accn = 0.0f;
        s_lg[g * 20 + 0] = plp;
#pragma unroll
        for (int k = 1; k < 20; ++k) {
            accn += __logf(ph + (float)(k - 1));
            s_lg[g * 20 + k] = accn - lnfact[k] + plp;
        }
    }
    __syncthreads();

    const int lane = tid & 63;
    const int q = __builtin_amdgcn_readfirstlane(tid >> 6);  // wave id 0..7
    const int s = blockIdx.x * 64 + lane;
    const bool valid = (s < ns);

    float acc[NT];
#pragma unroll
    for (int t = 0; t < NT; ++t) acc[t] = 0.0f;
    float hacc = 0.0f;

    float4 cv = make_float4(0.f, 0.f, 0.f, 0.f);
    float sf = 1.0f;
    if (valid) {
        cv = *reinterpret_cast<const float4*>(cov + (size_t)s * 4);
        sf = sfv[s];
    }
    const float lsf  = __logf(sf);
    const float lsf2 = lsf * L2E;

    const int g0 = q * 16;   // wave-uniform gene strip

    // preload all 16 k values
    float kb[16];
#pragma unroll
    for (int g4 = 0; g4 < 4; ++g4) {
        float4 kv = make_float4(0.f, 0.f, 0.f, 0.f);
        if (valid)
            kv = *reinterpret_cast<const float4*>(expr + (size_t)s * NG + g0 + g4 * 4);
        kb[g4 * 4 + 0] = kv.x; kb[g4 * 4 + 1] = kv.y;
        kb[g4 * 4 + 2] = kv.z; kb[g4 * 4 + 3] = kv.w;
    }

#pragma unroll 2
    for (int gg = 0; gg < 16; ++gg) {
        const int g = g0 + gg;
        const uint4* eu = (const uint4*)&s_e16[g * 32];
        uint4 E0 = eu[0];                                  // emd t0..7  (b128)
        uint4 E1 = eu[1];                                  // emd t8..15 (b128)
        uint4 M0 = eu[2];                                  // md  t0..7  (b128)
        uint4 M1 = eu[3];                                  // md  t8..15 (b128)
        float4 bv = *(const float4*)&s_gt[g * 8];          // b0..b3 (b128)
        float  ph = s_gt[g * 8 + 4];                       // b32

        float e = fmaf(bv.w, cv.w, fmaf(bv.z, cv.z, fmaf(bv.y, cv.y, bv.x * cv.x)));
        float c = EXP2F(fmaf(e, L2E, lsf2));               // sf * exp(e)
        float kf = kb[gg];
        float lg = s_lg[g * 20 + (int)kf];                 // per-lane gather (b32)
        hacc += fmaf(kf, lsf + e, lg);
        float nkp2 = -(kf + ph) * LN2;

        float ee[16], mm[16];
        ee[0] = bf_lo(E0.x); ee[1] = bf_hi(E0.x); ee[2] = bf_lo(E0.y); ee[3] = bf_hi(E0.y);
        ee[4] = bf_lo(E0.z); ee[5] = bf_hi(E0.z); ee[6] = bf_lo(E0.w); ee[7] = bf_hi(E0.w);
        ee[8] = bf_lo(E1.x); ee[9] = bf_hi(E1.x); ee[10] = bf_lo(E1.y); ee[11] = bf_hi(E1.y);
        ee[12] = bf_lo(E1.z); ee[13] = bf_hi(E1.z); ee[14] = bf_lo(E1.w); ee[15] = bf_hi(E1.w);
        mm[0] = bf_lo(M0.x); mm[1] = bf_hi(M0.x); mm[2] = bf_lo(M0.y); mm[3] = bf_hi(M0.y);
        mm[4] = bf_lo(M0.z); mm[5] = bf_hi(M0.z); mm[6] = bf_lo(M0.w); mm[7] = bf_hi(M0.w);
        mm[8] = bf_lo(M1.x); mm[9] = bf_hi(M1.x); mm[10] = bf_lo(M1.y); mm[11] = bf_hi(M1.y);
        mm[12] = bf_lo(M1.z); mm[13] = bf_hi(M1.z); mm[14] = bf_lo(M1.w); mm[15] = bf_hi(M1.w);

#pragma unroll
        for (int t = 0; t < NT; ++t) {
            float v = fmaf(c, ee[t], ph);                  // mu + phi (registers)
            acc[t] = fmaf(nkp2, __log2f(v), fmaf(kf, mm[t], acc[t]));
        }
    }
#pragma unroll
    for (int t = 0; t < NT; ++t) acc[t] += hacc;

    // ---- tree reduction 8 -> 4 -> 2 -> 1, aliased onto the table LDS ----
    float (*red)[64][17] = (float (*)[64][17])s_mem;   // 4*64*17*4 = 17408 <= 22528
    __syncthreads();                                   // tables dead from here

    if (q >= 4) {
#pragma unroll
        for (int t = 0; t < NT; ++t) red[q - 4][lane][t] = acc[t];
    }
    __syncthreads();
    if (q < 4) {
#pragma unroll
        for (int t = 0; t < NT; ++t) acc[t] += red[q][lane][t];
    }
    __syncthreads();
    if (q == 2 || q == 3) {
#pragma unroll
        for (int t = 0; t < NT; ++t) red[q - 2][lane][t] = acc[t];
    }
    __syncthreads();
    if (q < 2) {
#pragma unroll
        for (int t = 0; t < NT; ++t) acc[t] += red[q][lane][t];
    }
    __syncthreads();
    if (q == 1) {
#pragma unroll
        for (int t = 0; t < NT; ++t) red[0][lane][t] = acc[t];
    }
    __syncthreads();
    if (q == 0) {
        float m = -1e30f;
#pragma unroll
        for (int t = 0; t < NT; ++t) {
            acc[t] += red[0][lane][t];
            m = fmaxf(m, acc[t]);
        }
        float sum = 0.0f;
#pragma unroll
        for (int t = 0; t < NT; ++t) sum += __expf(acc[t] - m);
        float lp = m + __logf(sum);
        if (!valid) lp = 0.0f;
#pragma unroll
        for (int off = 32; off > 0; off >>= 1) lp += __shfl_down(lp, off);
        if (lane == 0) atomicAdd(out, lp);
    }
}

extern "C" void kernel_launch(void* const* d_in, const int* in_sizes, int n_in,
                              void* d_out, int out_size, void* d_ws, size_t ws_size,
                              hipStream_t stream) {
    const float* delta = (const float*)d_in[0];
    const float* beta  = (const float*)d_in[1];
    const float* phi   = (const float*)d_in[2];
    const float* expr  = (const float*)d_in[3];
    const float* cov   = (const float*)d_in[4];
    const float* sf    = (const float*)d_in[5];
    const float* mo    = (const float*)d_in[6];
    float* out = (float*)d_out;
    const int ns = in_sizes[5];

    zero_out<<<1, 64, 0, stream>>>(out);
    const int tiles = (ns + 63) / 64;
    nb_main<<<tiles, 512, 0, stream>>>(delta, beta, phi, mo, expr, cov, sf, out, ns);
}